// Round 5
// baseline (1445.729 us; speedup 1.0000x reference)
//
#include <hip/hip_runtime.h>
#include <hip/hip_fp16.h>

#define N_NODES  100000
#define N_EDGES  1600000
#define N_GRAPHS 512
#define DIM      128
#define EDGE_DIM 16
#define BN_EPS   1e-5f

typedef _Float16 h2 __attribute__((ext_vector_type(2)));

#if defined(__has_builtin)
#if __has_builtin(__builtin_amdgcn_fdot2)
#define HAVE_FDOT2 1
#endif
#endif

// ============================ CSR build ============================

__global__ __launch_bounds__(256) void k_hist(const int* __restrict__ dst,
                                              int* __restrict__ deg) {
    int e = blockIdx.x * 256 + threadIdx.x;
    if (e < N_EDGES) atomicAdd(&deg[dst[e]], 1);
}

__global__ __launch_bounds__(256) void k_scan1(const int* __restrict__ deg,
                                               int* __restrict__ rowptr1,
                                               int* __restrict__ sums, int N) {
    __shared__ int sc[256];
    int t = threadIdx.x;
    int base = blockIdx.x * 1024 + t * 4;
    int v0 = (base + 0 < N) ? deg[base + 0] : 0;
    int v1 = (base + 1 < N) ? deg[base + 1] : 0;
    int v2 = (base + 2 < N) ? deg[base + 2] : 0;
    int v3 = (base + 3 < N) ? deg[base + 3] : 0;
    v1 += v0; v2 += v1; v3 += v2;
    sc[t] = v3;
    __syncthreads();
    for (int o = 1; o < 256; o <<= 1) {
        int add = (t >= o) ? sc[t - o] : 0;
        __syncthreads();
        sc[t] += add;
        __syncthreads();
    }
    int prefix = sc[t] - v3;
    if (base + 0 < N) rowptr1[base + 0] = v0 + prefix;
    if (base + 1 < N) rowptr1[base + 1] = v1 + prefix;
    if (base + 2 < N) rowptr1[base + 2] = v2 + prefix;
    if (base + 3 < N) rowptr1[base + 3] = v3 + prefix;
    if (t == 255) sums[blockIdx.x] = sc[255];
}

__global__ __launch_bounds__(256) void k_scan2(int* __restrict__ sums, int n) {
    __shared__ int sc[256];
    int t = threadIdx.x;
    int v = (t < n) ? sums[t] : 0;
    sc[t] = v;
    __syncthreads();
    for (int o = 1; o < 256; o <<= 1) {
        int add = (t >= o) ? sc[t - o] : 0;
        __syncthreads();
        sc[t] += add;
        __syncthreads();
    }
    if (t < n) sums[t] = sc[t];
}

__global__ __launch_bounds__(256) void k_scan3(int* __restrict__ rowptr,
                                               int* __restrict__ cursor,
                                               const int* __restrict__ sums, int N) {
    int c = blockIdx.x;
    int off = (c == 0) ? 0 : sums[c - 1];
    int t = threadIdx.x;
    int base = c * 1024 + t * 4;
#pragma unroll
    for (int i = 0; i < 4; i++) {
        int g = base + i;
        if (g < N) {
            int val = rowptr[1 + g] + off;
            rowptr[1 + g] = val;
            if (g + 1 < N) cursor[g + 1] = val;
        }
    }
    if (c == 0 && t == 0) { rowptr[0] = 0; cursor[0] = 0; }
}

// fill CSR: src index + gather edge_attr row (fp16) into CSR order
__global__ __launch_bounds__(256) void k_fill(const int* __restrict__ src,
                                              const int* __restrict__ dst,
                                              const float* __restrict__ edge_attr,
                                              int* __restrict__ cursor,
                                              int* __restrict__ csr_src,
                                              uint4* __restrict__ csr_ea) {
    int e = blockIdx.x * 256 + threadIdx.x;
    if (e < N_EDGES) {
        int d = dst[e];
        int p = atomicAdd(&cursor[d], 1);
        csr_src[p] = src[e];
        const float4* ea = (const float4*)(edge_attr + (size_t)e * EDGE_DIM);
        float4 a0 = ea[0], a1 = ea[1], a2 = ea[2], a3 = ea[3];
        union { __half h[16]; uint4 q[2]; } u;
        u.h[0]  = __float2half(a0.x); u.h[1]  = __float2half(a0.y);
        u.h[2]  = __float2half(a0.z); u.h[3]  = __float2half(a0.w);
        u.h[4]  = __float2half(a1.x); u.h[5]  = __float2half(a1.y);
        u.h[6]  = __float2half(a1.z); u.h[7]  = __float2half(a1.w);
        u.h[8]  = __float2half(a2.x); u.h[9]  = __float2half(a2.y);
        u.h[10] = __float2half(a2.z); u.h[11] = __float2half(a2.w);
        u.h[12] = __float2half(a3.x); u.h[13] = __float2half(a3.y);
        u.h[14] = __float2half(a3.z); u.h[15] = __float2half(a3.w);
        uint4* o = csr_ea + (size_t)p * 2;
        o[0] = u.q[0]; o[1] = u.q[1];
    }
}

// ==================== GINE message + aggregate ====================
// One wave per node; lane owns features {2*lane, 2*lane+1}.
// agg[node] = x[node] + sum_e relu(x[src_e] + ea_e @ le_w + le_b)
union EaU { uint4 q[2]; h2 p[8]; };

__device__ __forceinline__ void edge_acc(float2 xr, uint4 q0, uint4 q1,
                                         const h2* wl0p, const h2* wl1p,
                                         float b0, float b1,
                                         float& acc0, float& acc1) {
    EaU u; u.q[0] = q0; u.q[1] = q1;
    float e0 = b0, e1 = b1;
#if HAVE_FDOT2
#pragma unroll
    for (int j = 0; j < 8; j++) {
        e0 = __builtin_amdgcn_fdot2(u.p[j], wl0p[j], e0, false);
        e1 = __builtin_amdgcn_fdot2(u.p[j], wl1p[j], e1, false);
    }
#else
#pragma unroll
    for (int j = 0; j < 8; j++) {
        float ax = (float)u.p[j].x, ay = (float)u.p[j].y;
        e0 = fmaf(ax, (float)wl0p[j].x, fmaf(ay, (float)wl0p[j].y, e0));
        e1 = fmaf(ax, (float)wl1p[j].x, fmaf(ay, (float)wl1p[j].y, e1));
    }
#endif
    acc0 += fmaxf(xr.x + e0, 0.f);
    acc1 += fmaxf(xr.y + e1, 0.f);
}

__global__ __launch_bounds__(256) void k_gine_msg(const float* __restrict__ x,
                                                  const uint4* __restrict__ csr_ea,
                                                  const int* __restrict__ rowptr,
                                                  const int* __restrict__ csr_src,
                                                  const float* __restrict__ lew,
                                                  const float* __restrict__ leb,
                                                  float* __restrict__ agg) {
    int lane = threadIdx.x & 63;
    int node = blockIdx.x * 4 + (threadIdx.x >> 6);
    int f0 = lane * 2;

    h2 wl0p[8], wl1p[8];
#pragma unroll
    for (int j = 0; j < 8; j++) {
        h2 a, b;
        a.x = (_Float16)lew[(2 * j + 0) * DIM + f0];
        a.y = (_Float16)lew[(2 * j + 1) * DIM + f0];
        b.x = (_Float16)lew[(2 * j + 0) * DIM + f0 + 1];
        b.y = (_Float16)lew[(2 * j + 1) * DIM + f0 + 1];
        wl0p[j] = a; wl1p[j] = b;
    }
    float b0 = leb[f0], b1 = leb[f0 + 1];

    float2 xv = *(const float2*)(x + (size_t)node * DIM + f0);
    float acc0 = xv.x, acc1 = xv.y;

    int pbeg = __builtin_amdgcn_readfirstlane(rowptr[node]);
    int pend = __builtin_amdgcn_readfirstlane(rowptr[node + 1]);

    int p = pbeg;
    for (; p + 4 <= pend; p += 4) {
        int s0 = __builtin_amdgcn_readfirstlane(csr_src[p + 0]);
        int s1 = __builtin_amdgcn_readfirstlane(csr_src[p + 1]);
        int s2 = __builtin_amdgcn_readfirstlane(csr_src[p + 2]);
        int s3 = __builtin_amdgcn_readfirstlane(csr_src[p + 3]);

        const uint4* ea = csr_ea + (size_t)p * 2;
        uint4 a00 = ea[0], a01 = ea[1];
        uint4 a10 = ea[2], a11 = ea[3];
        uint4 a20 = ea[4], a21 = ea[5];
        uint4 a30 = ea[6], a31 = ea[7];

        float2 x0 = *(const float2*)(x + (size_t)s0 * DIM + f0);
        float2 x1 = *(const float2*)(x + (size_t)s1 * DIM + f0);
        float2 x2 = *(const float2*)(x + (size_t)s2 * DIM + f0);
        float2 x3 = *(const float2*)(x + (size_t)s3 * DIM + f0);

        edge_acc(x0, a00, a01, wl0p, wl1p, b0, b1, acc0, acc1);
        edge_acc(x1, a10, a11, wl0p, wl1p, b0, b1, acc0, acc1);
        edge_acc(x2, a20, a21, wl0p, wl1p, b0, b1, acc0, acc1);
        edge_acc(x3, a30, a31, wl0p, wl1p, b0, b1, acc0, acc1);
    }
    for (; p < pend; p++) {
        int s0 = __builtin_amdgcn_readfirstlane(csr_src[p]);
        const uint4* ea = csr_ea + (size_t)p * 2;
        uint4 a0 = ea[0], a1 = ea[1];
        float2 x0 = *(const float2*)(x + (size_t)s0 * DIM + f0);
        edge_acc(x0, a0, a1, wl0p, wl1p, b0, b1, acc0, acc1);
    }

    float2 o; o.x = acc0; o.y = acc1;
    *(float2*)(agg + (size_t)node * DIM + f0) = o;
}

// ======================= node GEMM (M x 128 @ 128 x 128) =======================
// MODE 0: out = A@W+bias; column sum/sumsq atomically into colstat  (pre-BN hidden + stats)
// MODE 1: in = relu(bnA*A+bnC) (coef from colstat/gamma/beta); out = relu(in@W+bias)
// MODE 2: like MODE 1 but no store of out; atomicAdd rows into pooled[batch[row]]
template <int MODE>
__global__ __launch_bounds__(256) void k_gemm(const float* __restrict__ A,
                                              const float* __restrict__ W,
                                              const float* __restrict__ bias,
                                              float* __restrict__ colstat,   // MODE0: out, MODE1/2: in
                                              const float* __restrict__ gamma,
                                              const float* __restrict__ beta,
                                              const int* __restrict__ batch,
                                              float* __restrict__ pooled,
                                              float* __restrict__ out, int M) {
    __shared__ float As[32][DIM];
    __shared__ float cA[DIM], cB[DIM];
    int t = threadIdx.x;
    int rbase = blockIdx.x * 32;

    if (MODE != 0) {
        if (t < DIM) {
            float inv_n = 1.f / (float)N_NODES;
            float mean = colstat[t] * inv_n;
            float var = colstat[DIM + t] * inv_n - mean * mean;
            float a = gamma[t] * rsqrtf(var + BN_EPS);
            cA[t] = a;
            cB[t] = beta[t] - mean * a;
        }
        __syncthreads();
    }

#pragma unroll
    for (int i = 0; i < 16; i++) {
        int idx = t + i * 256;
        int r = idx >> 7, c = idx & 127;
        int gr = rbase + r;
        float v = (gr < M) ? A[(size_t)gr * DIM + c] : 0.f;
        if (MODE != 0) {
            v = cA[c] * v + cB[c];
            v = v > 0.f ? v : 0.f;
        }
        As[r][c] = v;
    }
    __syncthreads();

    int cq = (t & 31) * 4;
    int rg = (t >> 5) * 4;
    float acc[4][4] = {{0.f}};

    for (int k = 0; k < DIM; k++) {
        float4 w = *(const float4*)&W[(size_t)k * DIM + cq];
        float a0 = As[rg + 0][k], a1 = As[rg + 1][k];
        float a2 = As[rg + 2][k], a3 = As[rg + 3][k];
        acc[0][0] += a0 * w.x; acc[0][1] += a0 * w.y; acc[0][2] += a0 * w.z; acc[0][3] += a0 * w.w;
        acc[1][0] += a1 * w.x; acc[1][1] += a1 * w.y; acc[1][2] += a1 * w.z; acc[1][3] += a1 * w.w;
        acc[2][0] += a2 * w.x; acc[2][1] += a2 * w.y; acc[2][2] += a2 * w.z; acc[2][3] += a2 * w.w;
        acc[3][0] += a3 * w.x; acc[3][1] += a3 * w.y; acc[3][2] += a3 * w.z; acc[3][3] += a3 * w.w;
    }

    float4 bb = *(const float4*)&bias[cq];
    float o[4][4];
#pragma unroll
    for (int i = 0; i < 4; i++) {
        o[i][0] = acc[i][0] + bb.x;
        o[i][1] = acc[i][1] + bb.y;
        o[i][2] = acc[i][2] + bb.z;
        o[i][3] = acc[i][3] + bb.w;
        if (MODE != 0) {
#pragma unroll
            for (int j = 0; j < 4; j++) o[i][j] = o[i][j] > 0.f ? o[i][j] : 0.f;
        }
    }

    if (MODE != 2) {
#pragma unroll
        for (int i = 0; i < 4; i++) {
            int gr = rbase + rg + i;
            if (gr < M) {
                float4 v; v.x = o[i][0]; v.y = o[i][1]; v.z = o[i][2]; v.w = o[i][3];
                *(float4*)&out[(size_t)gr * DIM + cq] = v;
            }
        }
    }

    if (MODE == 0) {
        // column stats over this block's valid rows -> LDS reduce -> atomics
        float s[4] = {0.f, 0.f, 0.f, 0.f}, q[4] = {0.f, 0.f, 0.f, 0.f};
#pragma unroll
        for (int i = 0; i < 4; i++) {
            int gr = rbase + rg + i;
            if (gr < M) {
#pragma unroll
                for (int j = 0; j < 4; j++) {
                    s[j] += o[i][j];
                    q[j] += o[i][j] * o[i][j];
                }
            }
        }
        __syncthreads();                 // done reading As; reuse as scratch
        float* s1 = &As[0][0];           // [8][128]
        float* s2 = &As[8][0];           // [8][128]
        int rgi = t >> 5;
#pragma unroll
        for (int j = 0; j < 4; j++) {
            s1[rgi * DIM + cq + j] = s[j];
            s2[rgi * DIM + cq + j] = q[j];
        }
        __syncthreads();
        if (rgi == 0) {
#pragma unroll
            for (int j = 0; j < 4; j++) {
                float ts = 0.f, tq = 0.f;
#pragma unroll
                for (int k = 0; k < 8; k++) {
                    ts += s1[k * DIM + cq + j];
                    tq += s2[k * DIM + cq + j];
                }
                atomicAdd(&colstat[cq + j], ts);
                atomicAdd(&colstat[DIM + cq + j], tq);
            }
        }
    }

    if (MODE == 2) {
        int gr0 = rbase + rg;
        int b0 = (gr0 + 0 < M) ? batch[gr0 + 0] : -1;
        int b1 = (gr0 + 1 < M) ? batch[gr0 + 1] : -1;
        int b2 = (gr0 + 2 < M) ? batch[gr0 + 2] : -1;
        int b3 = (gr0 + 3 < M) ? batch[gr0 + 3] : -1;
        if (b0 == b3 && b0 >= 0) {
#pragma unroll
            for (int j = 0; j < 4; j++) {
                float v = o[0][j] + o[1][j] + o[2][j] + o[3][j];
                atomicAdd(&pooled[(size_t)b0 * DIM + cq + j], v);
            }
        } else {
            int bs[4] = {b0, b1, b2, b3};
#pragma unroll
            for (int i = 0; i < 4; i++) {
                if (bs[i] >= 0) {
#pragma unroll
                    for (int j = 0; j < 4; j++)
                        atomicAdd(&pooled[(size_t)bs[i] * DIM + cq + j], o[i][j]);
                }
            }
        }
    }
}

// ===================== classifier =====================
__global__ __launch_bounds__(64) void k_cls(const float* __restrict__ pooled,
                                            const float* __restrict__ Wc1,
                                            const float* __restrict__ bc1,
                                            const float* __restrict__ Wc2,
                                            const float* __restrict__ bc2,
                                            float* __restrict__ out) {
    __shared__ float row[DIM];
    __shared__ float t1[64];
    int g = blockIdx.x, t = threadIdx.x;
    row[t] = pooled[g * DIM + t];
    row[64 + t] = pooled[g * DIM + 64 + t];
    __syncthreads();
    float acc = bc1[t];
    for (int k = 0; k < DIM; k++) acc += row[k] * Wc1[k * 64 + t];
    t1[t] = acc > 0.f ? acc : 0.f;
    __syncthreads();
    if (t < 2) {
        float o = bc2[t];
        for (int j = 0; j < 64; j++) o += t1[j] * Wc2[j * 2 + t];
        out[g * 2 + t] = o;
    }
}

// ============================ launch ============================

extern "C" void kernel_launch(void* const* d_in, const int* in_sizes, int n_in,
                              void* d_out, int out_size, void* d_ws, size_t ws_size,
                              hipStream_t stream) {
    const float* x          = (const float*)d_in[0];
    const int*   edge_index = (const int*)d_in[1];
    const float* edge_attr  = (const float*)d_in[2];
    const int*   batch      = (const int*)d_in[3];
    const float* le1_w = (const float*)d_in[4];
    const float* le1_b = (const float*)d_in[5];
    const float* W11   = (const float*)d_in[6];
    const float* b11   = (const float*)d_in[7];
    const float* g1    = (const float*)d_in[8];
    const float* bt1   = (const float*)d_in[9];
    const float* W12   = (const float*)d_in[10];
    const float* b12   = (const float*)d_in[11];
    const float* le2_w = (const float*)d_in[12];
    const float* le2_b = (const float*)d_in[13];
    const float* W21   = (const float*)d_in[14];
    const float* b21   = (const float*)d_in[15];
    const float* g2    = (const float*)d_in[16];
    const float* bt2   = (const float*)d_in[17];
    const float* W22   = (const float*)d_in[18];
    const float* b22   = (const float*)d_in[19];
    const float* Wc1   = (const float*)d_in[20];
    const float* bc1   = (const float*)d_in[21];
    const float* Wc2   = (const float*)d_in[22];
    const float* bc2   = (const float*)d_in[23];
    float* out = (float*)d_out;

    const int* srcp = edge_index;
    const int* dstp = edge_index + N_EDGES;

    char* ws = (char*)d_ws;
    size_t off = 0;
    auto carve = [&](size_t bytes) -> char* {
        char* p = ws + off;
        off += (bytes + 255) & ~(size_t)255;
        return p;
    };
    float* X0      = (float*)carve((size_t)N_NODES * DIM * 4);   // 51.2 MB
    float* X1      = (float*)carve((size_t)N_NODES * DIM * 4);   // 51.2 MB
    int*   rowptr  = (int*)carve((size_t)(N_NODES + 1) * 4);
    int*   cursor  = (int*)carve((size_t)N_NODES * 4);           // also deg
    int*   sums    = (int*)carve(256 * 4);
    int*   csr_src = (int*)carve((size_t)N_EDGES * 4);           // 6.4 MB
    uint4* csr_ea  = (uint4*)carve((size_t)N_EDGES * 32);        // fp16, 51.2 MB
    // contiguous zero region: colstat1 | colstat2 | pooled
    float* zreg    = (float*)carve((2 * DIM + 2 * DIM + (size_t)N_GRAPHS * DIM) * 4);
    float* colstat1 = zreg;
    float* colstat2 = zreg + 2 * DIM;
    float* pooled   = zreg + 4 * DIM;
    (void)ws_size; (void)in_sizes; (void)n_in; (void)out_size;

    const int nch = (N_NODES + 1023) / 1024;   // 98
    const int ngb = (N_NODES + 31) / 32;       // 3125

    // --- zero scratch ---
    hipMemsetAsync(cursor, 0, (size_t)N_NODES * 4, stream);
    hipMemsetAsync(zreg, 0, (4 * DIM + (size_t)N_GRAPHS * DIM) * 4, stream);

    // --- CSR build + fp16 edge_attr gather ---
    k_hist<<<(N_EDGES + 255) / 256, 256, 0, stream>>>(dstp, cursor);
    k_scan1<<<nch, 256, 0, stream>>>(cursor, rowptr + 1, sums, N_NODES);
    k_scan2<<<1, 256, 0, stream>>>(sums, nch);
    k_scan3<<<nch, 256, 0, stream>>>(rowptr, cursor, sums, N_NODES);
    k_fill<<<(N_EDGES + 255) / 256, 256, 0, stream>>>(srcp, dstp, edge_attr, cursor,
                                                      csr_src, csr_ea);

    // --- layer 1 ---
    k_gine_msg<<<N_NODES / 4, 256, 0, stream>>>(x, csr_ea, rowptr, csr_src, le1_w, le1_b, X0);
    k_gemm<0><<<ngb, 256, 0, stream>>>(X0, W11, b11, colstat1, nullptr, nullptr,
                                       nullptr, nullptr, X1, N_NODES);
    k_gemm<1><<<ngb, 256, 0, stream>>>(X1, W12, b12, colstat1, g1, bt1,
                                       nullptr, nullptr, X0, N_NODES);

    // --- layer 2 ---
    k_gine_msg<<<N_NODES / 4, 256, 0, stream>>>(X0, csr_ea, rowptr, csr_src, le2_w, le2_b, X1);
    k_gemm<0><<<ngb, 256, 0, stream>>>(X1, W21, b21, colstat2, nullptr, nullptr,
                                       nullptr, nullptr, X0, N_NODES);
    k_gemm<2><<<ngb, 256, 0, stream>>>(X0, W22, b22, colstat2, g2, bt2,
                                       batch, pooled, nullptr, N_NODES);

    // --- classifier ---
    k_cls<<<N_GRAPHS, 64, 0, stream>>>(pooled, Wc1, bc1, Wc2, bc2, out);
}

// Round 7
// 946.371 us; speedup vs baseline: 1.5277x; 1.5277x over previous
//
#include <hip/hip_runtime.h>
#include <hip/hip_fp16.h>

#define N_NODES  100000
#define N_EDGES  1600000
#define N_GRAPHS 512
#define DIM      128
#define EDGE_DIM 16
#define BN_EPS   1e-5f
#define NGB      3125          // (N_NODES+31)/32 gemm blocks

typedef _Float16 h2 __attribute__((ext_vector_type(2)));

#if defined(__has_builtin)
#if __has_builtin(__builtin_amdgcn_fdot2)
#define HAVE_FDOT2 1
#endif
#endif

// ============================ CSR build ============================

__global__ __launch_bounds__(256) void k_hist(const int* __restrict__ dst,
                                              int* __restrict__ deg) {
    int e = blockIdx.x * 256 + threadIdx.x;
    if (e < N_EDGES) atomicAdd(&deg[dst[e]], 1);
}

__global__ __launch_bounds__(256) void k_scan1(const int* __restrict__ deg,
                                               int* __restrict__ rowptr1,
                                               int* __restrict__ sums, int N) {
    __shared__ int sc[256];
    int t = threadIdx.x;
    int base = blockIdx.x * 1024 + t * 4;
    int v0 = (base + 0 < N) ? deg[base + 0] : 0;
    int v1 = (base + 1 < N) ? deg[base + 1] : 0;
    int v2 = (base + 2 < N) ? deg[base + 2] : 0;
    int v3 = (base + 3 < N) ? deg[base + 3] : 0;
    v1 += v0; v2 += v1; v3 += v2;
    sc[t] = v3;
    __syncthreads();
    for (int o = 1; o < 256; o <<= 1) {
        int add = (t >= o) ? sc[t - o] : 0;
        __syncthreads();
        sc[t] += add;
        __syncthreads();
    }
    int prefix = sc[t] - v3;
    if (base + 0 < N) rowptr1[base + 0] = v0 + prefix;
    if (base + 1 < N) rowptr1[base + 1] = v1 + prefix;
    if (base + 2 < N) rowptr1[base + 2] = v2 + prefix;
    if (base + 3 < N) rowptr1[base + 3] = v3 + prefix;
    if (t == 255) sums[blockIdx.x] = sc[255];
}

__global__ __launch_bounds__(256) void k_scan2(int* __restrict__ sums, int n) {
    __shared__ int sc[256];
    int t = threadIdx.x;
    int v = (t < n) ? sums[t] : 0;
    sc[t] = v;
    __syncthreads();
    for (int o = 1; o < 256; o <<= 1) {
        int add = (t >= o) ? sc[t - o] : 0;
        __syncthreads();
        sc[t] += add;
        __syncthreads();
    }
    if (t < n) sums[t] = sc[t];
}

__global__ __launch_bounds__(256) void k_scan3(int* __restrict__ rowptr,
                                               int* __restrict__ cursor,
                                               const int* __restrict__ sums, int N) {
    int c = blockIdx.x;
    int off = (c == 0) ? 0 : sums[c - 1];
    int t = threadIdx.x;
    int base = c * 1024 + t * 4;
#pragma unroll
    for (int i = 0; i < 4; i++) {
        int g = base + i;
        if (g < N) {
            int val = rowptr[1 + g] + off;
            rowptr[1 + g] = val;
            if (g + 1 < N) cursor[g + 1] = val;
        }
    }
    if (c == 0 && t == 0) { rowptr[0] = 0; cursor[0] = 0; }
}

// fill CSR: src index + gather edge_attr row (fp16) into CSR order
__global__ __launch_bounds__(256) void k_fill(const int* __restrict__ src,
                                              const int* __restrict__ dst,
                                              const float* __restrict__ edge_attr,
                                              int* __restrict__ cursor,
                                              int* __restrict__ csr_src,
                                              uint4* __restrict__ csr_ea) {
    int e = blockIdx.x * 256 + threadIdx.x;
    if (e < N_EDGES) {
        int d = dst[e];
        int p = atomicAdd(&cursor[d], 1);
        csr_src[p] = src[e];
        const float4* ea = (const float4*)(edge_attr + (size_t)e * EDGE_DIM);
        float4 a0 = ea[0], a1 = ea[1], a2 = ea[2], a3 = ea[3];
        union { __half h[16]; uint4 q[2]; } u;
        u.h[0]  = __float2half(a0.x); u.h[1]  = __float2half(a0.y);
        u.h[2]  = __float2half(a0.z); u.h[3]  = __float2half(a0.w);
        u.h[4]  = __float2half(a1.x); u.h[5]  = __float2half(a1.y);
        u.h[6]  = __float2half(a1.z); u.h[7]  = __float2half(a1.w);
        u.h[8]  = __float2half(a2.x); u.h[9]  = __float2half(a2.y);
        u.h[10] = __float2half(a2.z); u.h[11] = __float2half(a2.w);
        u.h[12] = __float2half(a3.x); u.h[13] = __float2half(a3.y);
        u.h[14] = __float2half(a3.z); u.h[15] = __float2half(a3.w);
        uint4* o = csr_ea + (size_t)p * 2;
        o[0] = u.q[0]; o[1] = u.q[1];
    }
}

// ==================== GINE message + aggregate ====================
union EaU { uint4 q[2]; h2 p[8]; };

__device__ __forceinline__ void edge_acc(float2 xr, uint4 q0, uint4 q1,
                                         const h2* wl0p, const h2* wl1p,
                                         float b0, float b1,
                                         float& acc0, float& acc1) {
    EaU u; u.q[0] = q0; u.q[1] = q1;
    float e0 = b0, e1 = b1;
#if HAVE_FDOT2
#pragma unroll
    for (int j = 0; j < 8; j++) {
        e0 = __builtin_amdgcn_fdot2(u.p[j], wl0p[j], e0, false);
        e1 = __builtin_amdgcn_fdot2(u.p[j], wl1p[j], e1, false);
    }
#else
#pragma unroll
    for (int j = 0; j < 8; j++) {
        float ax = (float)u.p[j].x, ay = (float)u.p[j].y;
        e0 = fmaf(ax, (float)wl0p[j].x, fmaf(ay, (float)wl0p[j].y, e0));
        e1 = fmaf(ax, (float)wl1p[j].x, fmaf(ay, (float)wl1p[j].y, e1));
    }
#endif
    acc0 += fmaxf(xr.x + e0, 0.f);
    acc1 += fmaxf(xr.y + e1, 0.f);
}

__global__ __launch_bounds__(256) void k_gine_msg(const float* __restrict__ x,
                                                  const uint4* __restrict__ csr_ea,
                                                  const int* __restrict__ rowptr,
                                                  const int* __restrict__ csr_src,
                                                  const float* __restrict__ lew,
                                                  const float* __restrict__ leb,
                                                  float* __restrict__ agg) {
    int lane = threadIdx.x & 63;
    int node = blockIdx.x * 4 + (threadIdx.x >> 6);
    int f0 = lane * 2;

    h2 wl0p[8], wl1p[8];
#pragma unroll
    for (int j = 0; j < 8; j++) {
        h2 a, b;
        a.x = (_Float16)lew[(2 * j + 0) * DIM + f0];
        a.y = (_Float16)lew[(2 * j + 1) * DIM + f0];
        b.x = (_Float16)lew[(2 * j + 0) * DIM + f0 + 1];
        b.y = (_Float16)lew[(2 * j + 1) * DIM + f0 + 1];
        wl0p[j] = a; wl1p[j] = b;
    }
    float b0 = leb[f0], b1 = leb[f0 + 1];

    float2 xv = *(const float2*)(x + (size_t)node * DIM + f0);
    float acc0 = xv.x, acc1 = xv.y;

    int pbeg = __builtin_amdgcn_readfirstlane(rowptr[node]);
    int pend = __builtin_amdgcn_readfirstlane(rowptr[node + 1]);

    int p = pbeg;
    for (; p + 4 <= pend; p += 4) {
        int s0 = __builtin_amdgcn_readfirstlane(csr_src[p + 0]);
        int s1 = __builtin_amdgcn_readfirstlane(csr_src[p + 1]);
        int s2 = __builtin_amdgcn_readfirstlane(csr_src[p + 2]);
        int s3 = __builtin_amdgcn_readfirstlane(csr_src[p + 3]);

        const uint4* ea = csr_ea + (size_t)p * 2;
        uint4 a00 = ea[0], a01 = ea[1];
        uint4 a10 = ea[2], a11 = ea[3];
        uint4 a20 = ea[4], a21 = ea[5];
        uint4 a30 = ea[6], a31 = ea[7];

        float2 x0 = *(const float2*)(x + (size_t)s0 * DIM + f0);
        float2 x1 = *(const float2*)(x + (size_t)s1 * DIM + f0);
        float2 x2 = *(const float2*)(x + (size_t)s2 * DIM + f0);
        float2 x3 = *(const float2*)(x + (size_t)s3 * DIM + f0);

        edge_acc(x0, a00, a01, wl0p, wl1p, b0, b1, acc0, acc1);
        edge_acc(x1, a10, a11, wl0p, wl1p, b0, b1, acc0, acc1);
        edge_acc(x2, a20, a21, wl0p, wl1p, b0, b1, acc0, acc1);
        edge_acc(x3, a30, a31, wl0p, wl1p, b0, b1, acc0, acc1);
    }
    for (; p < pend; p++) {
        int s0 = __builtin_amdgcn_readfirstlane(csr_src[p]);
        const uint4* ea = csr_ea + (size_t)p * 2;
        uint4 a0 = ea[0], a1 = ea[1];
        float2 x0 = *(const float2*)(x + (size_t)s0 * DIM + f0);
        edge_acc(x0, a0, a1, wl0p, wl1p, b0, b1, acc0, acc1);
    }

    float2 o; o.x = acc0; o.y = acc1;
    *(float2*)(agg + (size_t)node * DIM + f0) = o;
}

// ======================= node GEMM (M x 128 @ 128 x 128) =======================
// MODE 0: out = A@W+bias; per-block column sum/sumsq -> part[blk][256] (NO atomics)
// MODE 1: in = relu(bnA*A+bnC) (coef from colstat/gamma/beta); out = relu(in@W+bias)
// MODE 2: like MODE 1 but no out store; atomicAdd 4-row-reduced rows into pooled[batch]
template <int MODE>
__global__ __launch_bounds__(256) void k_gemm(const float* __restrict__ A,
                                              const float* __restrict__ W,
                                              const float* __restrict__ bias,
                                              const float* __restrict__ colstat,
                                              float* __restrict__ part,
                                              const float* __restrict__ gamma,
                                              const float* __restrict__ beta,
                                              const int* __restrict__ batch,
                                              float* __restrict__ pooled,
                                              float* __restrict__ out, int M) {
    __shared__ float As[32][DIM];
    __shared__ float cA[DIM], cB[DIM];
    int t = threadIdx.x;
    int rbase = blockIdx.x * 32;

    if (MODE != 0) {
        if (t < DIM) {
            float inv_n = 1.f / (float)N_NODES;
            float mean = colstat[t] * inv_n;
            float var = colstat[DIM + t] * inv_n - mean * mean;
            float a = gamma[t] * rsqrtf(var + BN_EPS);
            cA[t] = a;
            cB[t] = beta[t] - mean * a;
        }
        __syncthreads();
    }

#pragma unroll
    for (int i = 0; i < 16; i++) {
        int idx = t + i * 256;
        int r = idx >> 7, c = idx & 127;
        int gr = rbase + r;
        float v = (gr < M) ? A[(size_t)gr * DIM + c] : 0.f;
        if (MODE != 0) {
            v = cA[c] * v + cB[c];
            v = v > 0.f ? v : 0.f;
        }
        As[r][c] = v;
    }
    __syncthreads();

    int cq = (t & 31) * 4;
    int rg = (t >> 5) * 4;
    float acc[4][4] = {{0.f}};

    for (int k = 0; k < DIM; k++) {
        float4 w = *(const float4*)&W[(size_t)k * DIM + cq];
        float a0 = As[rg + 0][k], a1 = As[rg + 1][k];
        float a2 = As[rg + 2][k], a3 = As[rg + 3][k];
        acc[0][0] += a0 * w.x; acc[0][1] += a0 * w.y; acc[0][2] += a0 * w.z; acc[0][3] += a0 * w.w;
        acc[1][0] += a1 * w.x; acc[1][1] += a1 * w.y; acc[1][2] += a1 * w.z; acc[1][3] += a1 * w.w;
        acc[2][0] += a2 * w.x; acc[2][1] += a2 * w.y; acc[2][2] += a2 * w.z; acc[2][3] += a2 * w.w;
        acc[3][0] += a3 * w.x; acc[3][1] += a3 * w.y; acc[3][2] += a3 * w.z; acc[3][3] += a3 * w.w;
    }

    float4 bb = *(const float4*)&bias[cq];
    float o[4][4];
#pragma unroll
    for (int i = 0; i < 4; i++) {
        o[i][0] = acc[i][0] + bb.x;
        o[i][1] = acc[i][1] + bb.y;
        o[i][2] = acc[i][2] + bb.z;
        o[i][3] = acc[i][3] + bb.w;
        if (MODE != 0) {
#pragma unroll
            for (int j = 0; j < 4; j++) o[i][j] = o[i][j] > 0.f ? o[i][j] : 0.f;
        }
    }

    if (MODE != 2) {
#pragma unroll
        for (int i = 0; i < 4; i++) {
            int gr = rbase + rg + i;
            if (gr < M) {
                float4 v; v.x = o[i][0]; v.y = o[i][1]; v.z = o[i][2]; v.w = o[i][3];
                *(float4*)&out[(size_t)gr * DIM + cq] = v;
            }
        }
    }

    if (MODE == 0) {
        // per-block column stats -> LDS reduce -> coalesced partial store (no atomics)
        float s[4] = {0.f, 0.f, 0.f, 0.f}, q[4] = {0.f, 0.f, 0.f, 0.f};
#pragma unroll
        for (int i = 0; i < 4; i++) {
            int gr = rbase + rg + i;
            if (gr < M) {
#pragma unroll
                for (int j = 0; j < 4; j++) {
                    s[j] += o[i][j];
                    q[j] += o[i][j] * o[i][j];
                }
            }
        }
        __syncthreads();                 // done reading As; reuse as scratch
        float* s1 = &As[0][0];           // [8][128]
        float* s2 = &As[8][0];           // [8][128]
        int rgi = t >> 5;
#pragma unroll
        for (int j = 0; j < 4; j++) {
            s1[rgi * DIM + cq + j] = s[j];
            s2[rgi * DIM + cq + j] = q[j];
        }
        __syncthreads();
        // 256 threads each reduce one of 256 stat slots (0..127 sum, 128..255 sumsq)
        float* srcp = (t < DIM) ? s1 : s2;
        int col = t & 127;
        float ts = 0.f;
#pragma unroll
        for (int k = 0; k < 8; k++) ts += srcp[k * DIM + col];
        part[(size_t)blockIdx.x * 256 + t] = ts;
    }

    if (MODE == 2) {
        int gr0 = rbase + rg;
        int b0 = (gr0 + 0 < M) ? batch[gr0 + 0] : -1;
        int b3 = (gr0 + 3 < M) ? batch[gr0 + 3] : -1;
        if (b0 == b3 && b0 >= 0) {
#pragma unroll
            for (int j = 0; j < 4; j++) {
                float v = o[0][j] + o[1][j] + o[2][j] + o[3][j];
                atomicAdd(&pooled[(size_t)b0 * DIM + cq + j], v);
            }
        } else {
            int bs[4];
            bs[0] = b0;
            bs[1] = (gr0 + 1 < M) ? batch[gr0 + 1] : -1;
            bs[2] = (gr0 + 2 < M) ? batch[gr0 + 2] : -1;
            bs[3] = b3;
#pragma unroll
            for (int i = 0; i < 4; i++) {
                if (bs[i] >= 0) {
#pragma unroll
                    for (int j = 0; j < 4; j++)
                        atomicAdd(&pooled[(size_t)bs[i] * DIM + cq + j], o[i][j]);
                }
            }
        }
    }
}

// ===================== partial-stats reduction =====================
// part[NGB][256] -> colstat[256]; grid 64 x 256 threads -> 64 atomics/address
__global__ __launch_bounds__(256) void k_redstats(const float* __restrict__ part,
                                                  float* __restrict__ colstat) {
    int t = threadIdx.x;
    float s = 0.f;
    for (int r = blockIdx.x; r < NGB; r += gridDim.x)
        s += part[(size_t)r * 256 + t];
    atomicAdd(&colstat[t], s);
}

// ===================== classifier =====================
__global__ __launch_bounds__(64) void k_cls(const float* __restrict__ pooled,
                                            const float* __restrict__ Wc1,
                                            const float* __restrict__ bc1,
                                            const float* __restrict__ Wc2,
                                            const float* __restrict__ bc2,
                                            float* __restrict__ out) {
    __shared__ float row[DIM];
    __shared__ float t1[64];
    int g = blockIdx.x, t = threadIdx.x;
    row[t] = pooled[g * DIM + t];
    row[64 + t] = pooled[g * DIM + 64 + t];
    __syncthreads();
    float acc = bc1[t];
    for (int k = 0; k < DIM; k++) acc += row[k] * Wc1[k * 64 + t];
    t1[t] = acc > 0.f ? acc : 0.f;
    __syncthreads();
    if (t < 2) {
        float o = bc2[t];
        for (int j = 0; j < 64; j++) o += t1[j] * Wc2[j * 2 + t];
        out[g * 2 + t] = o;
    }
}

// ============================ launch ============================

extern "C" void kernel_launch(void* const* d_in, const int* in_sizes, int n_in,
                              void* d_out, int out_size, void* d_ws, size_t ws_size,
                              hipStream_t stream) {
    const float* x          = (const float*)d_in[0];
    const int*   edge_index = (const int*)d_in[1];
    const float* edge_attr  = (const float*)d_in[2];
    const int*   batch      = (const int*)d_in[3];
    const float* le1_w = (const float*)d_in[4];
    const float* le1_b = (const float*)d_in[5];
    const float* W11   = (const float*)d_in[6];
    const float* b11   = (const float*)d_in[7];
    const float* g1    = (const float*)d_in[8];
    const float* bt1   = (const float*)d_in[9];
    const float* W12   = (const float*)d_in[10];
    const float* b12   = (const float*)d_in[11];
    const float* le2_w = (const float*)d_in[12];
    const float* le2_b = (const float*)d_in[13];
    const float* W21   = (const float*)d_in[14];
    const float* b21   = (const float*)d_in[15];
    const float* g2    = (const float*)d_in[16];
    const float* bt2   = (const float*)d_in[17];
    const float* W22   = (const float*)d_in[18];
    const float* b22   = (const float*)d_in[19];
    const float* Wc1   = (const float*)d_in[20];
    const float* bc1   = (const float*)d_in[21];
    const float* Wc2   = (const float*)d_in[22];
    const float* bc2   = (const float*)d_in[23];
    float* out = (float*)d_out;

    const int* srcp = edge_index;
    const int* dstp = edge_index + N_EDGES;

    char* ws = (char*)d_ws;
    size_t off = 0;
    auto carve = [&](size_t bytes) -> char* {
        char* p = ws + off;
        off += (bytes + 255) & ~(size_t)255;
        return p;
    };
    float* X0      = (float*)carve((size_t)N_NODES * DIM * 4);   // 51.2 MB
    float* X1      = (float*)carve((size_t)N_NODES * DIM * 4);   // 51.2 MB
    int*   rowptr  = (int*)carve((size_t)(N_NODES + 1) * 4);
    int*   cursor  = (int*)carve((size_t)N_NODES * 4);           // also deg
    int*   sums    = (int*)carve(256 * 4);
    int*   csr_src = (int*)carve((size_t)N_EDGES * 4);           // 6.4 MB
    uint4* csr_ea  = (uint4*)carve((size_t)N_EDGES * 32);        // fp16, 51.2 MB
    float* part    = (float*)carve((size_t)NGB * 256 * 4);       // 3.2 MB
    // contiguous zero region: colstat1 | colstat2 | pooled
    float* zreg    = (float*)carve((2 * DIM + 2 * DIM + (size_t)N_GRAPHS * DIM) * 4);
    float* colstat1 = zreg;
    float* colstat2 = zreg + 2 * DIM;
    float* pooled   = zreg + 4 * DIM;
    (void)ws_size; (void)in_sizes; (void)n_in; (void)out_size;

    const int nch = (N_NODES + 1023) / 1024;   // 98

    // --- zero scratch ---
    hipMemsetAsync(cursor, 0, (size_t)N_NODES * 4, stream);
    hipMemsetAsync(zreg, 0, (4 * DIM + (size_t)N_GRAPHS * DIM) * 4, stream);

    // --- CSR build + fp16 edge_attr gather ---
    k_hist<<<(N_EDGES + 255) / 256, 256, 0, stream>>>(dstp, cursor);
    k_scan1<<<nch, 256, 0, stream>>>(cursor, rowptr + 1, sums, N_NODES);
    k_scan2<<<1, 256, 0, stream>>>(sums, nch);
    k_scan3<<<nch, 256, 0, stream>>>(rowptr, cursor, sums, N_NODES);
    k_fill<<<(N_EDGES + 255) / 256, 256, 0, stream>>>(srcp, dstp, edge_attr, cursor,
                                                      csr_src, csr_ea);

    // --- layer 1 ---
    k_gine_msg<<<N_NODES / 4, 256, 0, stream>>>(x, csr_ea, rowptr, csr_src, le1_w, le1_b, X0);
    k_gemm<0><<<NGB, 256, 0, stream>>>(X0, W11, b11, nullptr, part, nullptr, nullptr,
                                       nullptr, nullptr, X1, N_NODES);
    k_redstats<<<64, 256, 0, stream>>>(part, colstat1);
    k_gemm<1><<<NGB, 256, 0, stream>>>(X1, W12, b12, colstat1, nullptr, g1, bt1,
                                       nullptr, nullptr, X0, N_NODES);

    // --- layer 2 ---
    k_gine_msg<<<N_NODES / 4, 256, 0, stream>>>(X0, csr_ea, rowptr, csr_src, le2_w, le2_b, X1);
    k_gemm<0><<<NGB, 256, 0, stream>>>(X1, W21, b21, nullptr, part, nullptr, nullptr,
                                       nullptr, nullptr, X0, N_NODES);
    k_redstats<<<64, 256, 0, stream>>>(part, colstat2);
    k_gemm<2><<<NGB, 256, 0, stream>>>(X0, W22, b22, colstat2, nullptr, g2, bt2,
                                       batch, pooled, nullptr, N_NODES);

    // --- classifier ---
    k_cls<<<N_GRAPHS, 64, 0, stream>>>(pooled, Wc1, bc1, Wc2, bc2, out);
}